// Round 7
// baseline (5161.219 us; speedup 1.0000x reference)
//
#include <hip/hip_runtime.h>

#define NB 16
#define NP 4096
#define CF 64
#define NS 1024
#define NK 32
#define NROWS (NB*NS*NK)   // 524288

typedef float f32x4 __attribute__((ext_vector_type(4)));
typedef __bf16 bf16x8 __attribute__((ext_vector_type(8)));
typedef unsigned short u16x8 __attribute__((ext_vector_type(8)));

__device__ __forceinline__ unsigned short f2bf(float f){
  unsigned u = __float_as_uint(f);
  return (unsigned short)((u + 0x7FFFu + ((u>>16)&1u)) >> 16);
}
__device__ __forceinline__ float bf2f(unsigned short s){
  return __uint_as_float(((unsigned)s)<<16);
}

// DPP-assisted in-row max (xor1,2,4,8), literals required for dpp_ctrl.
__device__ __forceinline__ float dppmax_b1(float x){
  int y=__builtin_amdgcn_update_dpp(0,__float_as_int(x),0xB1,0xF,0xF,true);
  return fmaxf(x,__int_as_float(y));
}
__device__ __forceinline__ float dppmax_4e(float x){
  int y=__builtin_amdgcn_update_dpp(0,__float_as_int(x),0x4E,0xF,0xF,true);
  return fmaxf(x,__int_as_float(y));
}
__device__ __forceinline__ float dppmax_hm(float x){  // row_half_mirror (xor4)
  int y=__builtin_amdgcn_update_dpp(0,__float_as_int(x),0x141,0xF,0xF,true);
  return fmaxf(x,__int_as_float(y));
}
__device__ __forceinline__ float dppmax_m(float x){   // row_mirror (xor8)
  int y=__builtin_amdgcn_update_dpp(0,__float_as_int(x),0x140,0xF,0xF,true);
  return fmaxf(x,__int_as_float(y));
}

__device__ __forceinline__ float4 sel4(bool c, float4 a, float4 b){
  return make_float4(c?a.x:b.x, c?a.y:b.y, c?a.z:b.z, c?a.w:b.w);
}

// ---------------------------------------------------------------------------
// K1: furthest point sampling. One block (256 thr, 4 waves) per batch.
// Bit-exact vs numpy: strict-rounded scalar ops in reference association
// order ((dx*dx+dy*dy)+dz*dz). First-index argmax tie-break:
//   in-thread: depth-4 binary TREE on logical index order, cond = d[hi]>d[lo]
//              (strict > keeps lower index on tie); coords carried via
//              if-converted selects (no serial chain, no register indexing),
//   in-wave  : ballot + ffs keeps lowest lane (lane order == index order),
//   x-wave   : 3-node tournament keeps lower wid on ties.
// No LDS point mirror, no dependent P4[winner] read.
// ---------------------------------------------------------------------------
#define FPS_T 256
__global__ __launch_bounds__(FPS_T) void fps_kernel(const float* __restrict__ p,
                                                    float* __restrict__ qry){
  __shared__ float4 ebuf[2][4];
  const int b = blockIdx.x, tid = threadIdx.x;
  const int lane = tid & 63, wid = tid >> 6;
  const float* pb = p + (size_t)b*NP*3;
  float px[16], py[16], pz[16], dist[16];
#pragma unroll
  for (int g=0; g<4; g++){
    const int i0 = tid*16 + g*4;
    const float* src = pb + (size_t)i0*3;
    f32x4 a = *(const f32x4*)(src);
    f32x4 c = *(const f32x4*)(src+4);
    f32x4 d = *(const f32x4*)(src+8);
    px[g*4+0]=a[0]; py[g*4+0]=a[1]; pz[g*4+0]=a[2];
    px[g*4+1]=a[3]; py[g*4+1]=c[0]; pz[g*4+1]=c[1];
    px[g*4+2]=c[2]; py[g*4+2]=c[3]; pz[g*4+2]=d[0];
    px[g*4+3]=d[1]; py[g*4+3]=d[2]; pz[g*4+3]=d[3];
#pragma unroll
    for (int j=0;j<4;j++) dist[g*4+j]=1e10f;
  }
  float lx=pb[0], ly=pb[1], lz=pb[2];
  for (int t=0;t<NS;t++){
    if (tid==0){
      size_t o=(size_t)(b*NS+t)*3;
      qry[o+0]=lx; qry[o+1]=ly; qry[o+2]=lz;
    }
    // distance update (independent per point; throughput-bound)
#pragma unroll
    for (int j=0;j<16;j++){
      float dx=__fsub_rn(px[j],lx), dy=__fsub_rn(py[j],ly), dz=__fsub_rn(pz[j],lz);
      float d=__fadd_rn(__fadd_rn(__fmul_rn(dx,dx),__fmul_rn(dy,dy)),__fmul_rn(dz,dz));
      dist[j]=fminf(dist[j],d);
    }
    // in-thread argmax TREE with coord carry (depth 4, if-converted selects)
    float d_[16], X[16], Y[16], Z[16];
#pragma unroll
    for (int j=0;j<16;j++){ d_[j]=dist[j]; X[j]=px[j]; Y[j]=py[j]; Z[j]=pz[j]; }
#pragma unroll
    for (int s=1; s<16; s<<=1){
#pragma unroll
      for (int k=0; k<16; k+=2*s){
        bool c = d_[k+s] > d_[k];          // strict >: keep lower index on tie
        d_[k] = c ? d_[k+s] : d_[k];
        X[k]  = c ? X[k+s]  : X[k];
        Y[k]  = c ? Y[k+s]  : Y[k];
        Z[k]  = c ? Z[k+s]  : Z[k];
      }
    }
    const float bv = d_[0], wx = X[0], wy = Y[0], wz = Z[0];
    // wave max of bv: DPP butterfly in 16-lane rows, then 4 readlanes+scalar
    float m = bv;
    m = dppmax_b1(m);            // xor 1
    m = dppmax_4e(m);            // xor 2
    m = dppmax_hm(m);            // xor 4
    m = dppmax_m(m);             // xor 8
    unsigned m0 = (unsigned)__builtin_amdgcn_readlane(__float_as_int(m), 0);
    unsigned m1 = (unsigned)__builtin_amdgcn_readlane(__float_as_int(m), 16);
    unsigned m2 = (unsigned)__builtin_amdgcn_readlane(__float_as_int(m), 32);
    unsigned m3 = (unsigned)__builtin_amdgcn_readlane(__float_as_int(m), 48);
    unsigned ma = m0>m1?m0:m1, mb = m2>m3?m2:m3;
    unsigned mu = ma>mb?ma:mb;   // valid: dist >= 0 so u32 compare == f32
    // first lane holding the max (lane order == index order)
    unsigned long long ball = __ballot(__float_as_uint(bv)==mu);
    int srcl = (int)(__ffsll((long long)ball) - 1);
    float cx = __uint_as_float(__builtin_amdgcn_readlane(__float_as_int(wx), srcl));
    float cy = __uint_as_float(__builtin_amdgcn_readlane(__float_as_int(wy), srcl));
    float cz = __uint_as_float(__builtin_amdgcn_readlane(__float_as_int(wz), srcl));
    if (lane==0) ebuf[t&1][wid] = make_float4(cx,cy,cz,__uint_as_float(mu));
    __syncthreads();
    // tournament over 4 wave entries; strict > keeps lower wid on ties
    float4 e0=ebuf[t&1][0], e1=ebuf[t&1][1], e2=ebuf[t&1][2], e3=ebuf[t&1][3];
    float4 a01 = sel4(e1.w>e0.w, e1, e0);
    float4 a23 = sel4(e3.w>e2.w, e3, e2);
    float4 win = sel4(a23.w>a01.w, a23, a01);
    lx=win.x; ly=win.y; lz=win.z;
  }
}

// ---------------------------------------------------------------------------
// K2: ball query, wave-per-query ordered ballot scan.
// ---------------------------------------------------------------------------
#define BQ_T 512
__global__ __launch_bounds__(BQ_T) void ballq_kernel(const float* __restrict__ p,
                                                     const float* __restrict__ qry,
                                                     int* __restrict__ grp){
  __shared__ float PX[NP], PY[NP], PZ[NP];
  const int tid = threadIdx.x, lane = tid & 63, w = tid >> 6;  // 8 waves
  const int b  = blockIdx.x >> 7;          // 128 blocks per batch
  const int s0 = (blockIdx.x & 127) * 8;   // 8 queries per block
  const float* pb = p + (size_t)b*NP*3;
  for (int i = tid; i < NP; i += BQ_T){
    PX[i]=pb[i*3+0]; PY[i]=pb[i*3+1]; PZ[i]=pb[i*3+2];
  }
  __syncthreads();
  const int s = s0 + w;
  const float* q = qry + (size_t)(b*NS+s)*3;
  const float qx=q[0], qy=q[1], qz=q[2];
  int* out = grp + (size_t)(b*NS+s)*NK;
  const float RR = (float)(0.2*0.2);
  int cum = 0, first = 0;
  for (int j=0;j<NP/64;j++){
    const int idx = j*64 + lane;
    float dx=__fsub_rn(qx,PX[idx]), dy=__fsub_rn(qy,PY[idx]), dz=__fsub_rn(qz,PZ[idx]);
    float sq=__fadd_rn(__fadd_rn(__fmul_rn(dx,dx),__fmul_rn(dy,dy)),__fmul_rn(dz,dz));
    const bool in_r = (sq <= RR);
    unsigned long long ball = __ballot(in_r);
    if (ball){
      if (cum == 0) first = j*64 + (int)__builtin_ctzll(ball);
      int below = __builtin_amdgcn_mbcnt_hi((unsigned)(ball>>32),
                    __builtin_amdgcn_mbcnt_lo((unsigned)ball, 0));
      int pos = cum + below;
      if (in_r && pos < NK) out[pos] = idx;
      cum += (int)__popcll(ball);
      if (cum >= NK) break;
    }
  }
  const int cnt = cum < NK ? cum : NK;
  if (lane >= cnt && lane < NK) out[lane] = first;
}

// ---------------------------------------------------------------------------
// K3: zero stats slots (first-call 0xAA poison; finalize re-zeros afterwards)
// ---------------------------------------------------------------------------
__global__ void zero_slots_kernel(float* __restrict__ slots){
  int i = blockIdx.x*256 + threadIdx.x;
  if (i < 64*256) slots[i]=0.0f;
}

// ---------------------------------------------------------------------------
// K4: fused gather + layer0 GEMM (K=67 padded to 96) + pre-BN stats.
// ---------------------------------------------------------------------------
#define TPW 8
__global__ __launch_bounds__(256) void gemm0_kernel(const float* __restrict__ f,
    const float* __restrict__ p, const float* __restrict__ qry,
    const int* __restrict__ grp, const float* __restrict__ W0,
    const float* __restrict__ b0, unsigned short* __restrict__ ybuf,
    float* __restrict__ slots){
  const int tid=threadIdx.x, lane=tid&63, w=tid>>6;
  const int lg=lane>>4, lr=lane&15;
  bf16x8 bw[3][4];
#pragma unroll
  for (int kc=0;kc<3;kc++)
#pragma unroll
    for (int nt=0;nt<4;nt++){
      u16x8 t;
#pragma unroll
      for (int j=0;j<8;j++){
        int k = kc*32 + lg*8 + j, n = nt*16 + lr;
        float v = (k<67) ? W0[k*64+n] : 0.0f;
        t[j]=f2bf(v);
      }
      bw[kc][nt]=__builtin_bit_cast(bf16x8,t);
    }
  float bs[4];
#pragma unroll
  for (int nt=0;nt<4;nt++) bs[nt]=b0[nt*16+lr];
  float ssum[4]={0,0,0,0}, ssq[4]={0,0,0,0};
  const int base_row = blockIdx.x*512;
  const int b = base_row / (NS*NK);
  for (int ti=0;ti<TPW;ti++){
    const int R0 = base_row + (w*TPW+ti)*16;
    const int Ra = R0 + lr;
    const int idxp = grp[Ra];
    const float* frow = f + ((size_t)(b*NP+idxp))*64;
    f32x4 u0=*(const f32x4*)(frow + lg*8);
    f32x4 u1=*(const f32x4*)(frow + lg*8 + 4);
    f32x4 u2=*(const f32x4*)(frow + 32 + lg*8);
    f32x4 u3=*(const f32x4*)(frow + 36 + lg*8);
    u16x8 t0, t1;
#pragma unroll
    for (int j=0;j<4;j++){
      t0[j]=f2bf(u0[j]); t0[4+j]=f2bf(u1[j]);
      t1[j]=f2bf(u2[j]); t1[4+j]=f2bf(u3[j]);
    }
    u16x8 t2={0,0,0,0,0,0,0,0};
    if (lg==0){
      const int qidx = Ra >> 5;  // b*NS + s
      const float* pp = p + ((size_t)(b*NP+idxp))*3;
      const float* qq = qry + (size_t)qidx*3;
      t2[0]=f2bf(__fsub_rn(pp[0],qq[0]));
      t2[1]=f2bf(__fsub_rn(pp[1],qq[1]));
      t2[2]=f2bf(__fsub_rn(pp[2],qq[2]));
    }
    bf16x8 a0=__builtin_bit_cast(bf16x8,t0);
    bf16x8 a1=__builtin_bit_cast(bf16x8,t1);
    bf16x8 a2=__builtin_bit_cast(bf16x8,t2);
#pragma unroll
    for (int nt=0;nt<4;nt++){
      f32x4 acc={0,0,0,0};
      acc=__builtin_amdgcn_mfma_f32_16x16x32_bf16(a0,bw[0][nt],acc,0,0,0);
      acc=__builtin_amdgcn_mfma_f32_16x16x32_bf16(a1,bw[1][nt],acc,0,0,0);
      acc=__builtin_amdgcn_mfma_f32_16x16x32_bf16(a2,bw[2][nt],acc,0,0,0);
#pragma unroll
      for (int r=0;r<4;r++){
        float v = acc[r] + bs[nt];
        ssum[nt]+=v; ssq[nt]+=v*v;
        ybuf[(size_t)(R0 + lg*4 + r)*64 + nt*16 + lr] = f2bf(v);
      }
    }
  }
  float* slot = slots + (size_t)(blockIdx.x & 63)*256;
#pragma unroll
  for (int nt=0;nt<4;nt++){
    float s1=ssum[nt], s2=ssq[nt];
    s1 += __shfl_xor(s1,16); s1 += __shfl_xor(s1,32);
    s2 += __shfl_xor(s2,16); s2 += __shfl_xor(s2,32);
    if (lane<16){
      atomicAdd(slot + nt*16+lr, s1);
      atomicAdd(slot + 128 + nt*16+lr, s2);
    }
  }
}

// ---------------------------------------------------------------------------
// K5: finalize BN params for a layer; also re-zero slots for the next layer.
// ---------------------------------------------------------------------------
__global__ void finalize_kernel(float* __restrict__ slots,
                                const float* __restrict__ gamma,
                                const float* __restrict__ beta,
                                float* __restrict__ par, int Cc){
  const int c = threadIdx.x;  // 128 threads
  float s1=0.f, s2=0.f;
  for (int i=0;i<64;i++){ s1+=slots[i*256+c]; s2+=slots[i*256+128+c]; }
  const float invM = 1.0f/(float)NROWS;
  if (c<Cc){
    float mean = s1*invM;
    float var  = s2*invM - mean*mean;
    float scale = gamma[c]/sqrtf(var + 1e-5f);
    par[c]      = scale;
    par[128+c]  = beta[c] - mean*scale;
  }
  for (int i=0;i<64;i++){ slots[i*256+c]=0.f; slots[i*256+128+c]=0.f; }
}

// ---------------------------------------------------------------------------
// K6: layer1 = affine0+relu on y0, GEMM with W1 (64x64), stats; in-place y0->y1
// ---------------------------------------------------------------------------
__global__ __launch_bounds__(256) void gemm1_kernel(unsigned short* __restrict__ ybuf,
    const float* __restrict__ W, const float* __restrict__ bv,
    const float* __restrict__ par0, float* __restrict__ slots){
  const int tid=threadIdx.x, lane=tid&63, w=tid>>6;
  const int lg=lane>>4, lr=lane&15;
  float sc[2][8], sh[2][8];
#pragma unroll
  for (int kc=0;kc<2;kc++){
    int c0=kc*32+lg*8;
#pragma unroll
    for (int j=0;j<8;j++){ sc[kc][j]=par0[c0+j]; sh[kc][j]=par0[128+c0+j]; }
  }
  bf16x8 bw[2][4];
#pragma unroll
  for (int kc=0;kc<2;kc++)
#pragma unroll
    for (int nt=0;nt<4;nt++){
      u16x8 t;
#pragma unroll
      for (int j=0;j<8;j++){
        int k=kc*32+lg*8+j, n=nt*16+lr;
        t[j]=f2bf(W[k*64+n]);
      }
      bw[kc][nt]=__builtin_bit_cast(bf16x8,t);
    }
  float bs[4];
#pragma unroll
  for (int nt=0;nt<4;nt++) bs[nt]=bv[nt*16+lr];
  float ssum[4]={0,0,0,0}, ssq[4]={0,0,0,0};
  const int base_row = blockIdx.x*512;
  for (int ti=0;ti<TPW;ti++){
    const int R0 = base_row + (w*TPW+ti)*16;
    const unsigned short* yr = ybuf + (size_t)(R0+lr)*64;
    bf16x8 a[2];
#pragma unroll
    for (int kc=0;kc<2;kc++){
      u16x8 rv = *(const u16x8*)(yr + kc*32 + lg*8);
      u16x8 t;
#pragma unroll
      for (int j=0;j<8;j++){
        float v = bf2f(rv[j]);
        v = fmaxf(fmaf(v, sc[kc][j], sh[kc][j]), 0.f);
        t[j]=f2bf(v);
      }
      a[kc]=__builtin_bit_cast(bf16x8,t);
    }
#pragma unroll
    for (int nt=0;nt<4;nt++){
      f32x4 acc={0,0,0,0};
      acc=__builtin_amdgcn_mfma_f32_16x16x32_bf16(a[0],bw[0][nt],acc,0,0,0);
      acc=__builtin_amdgcn_mfma_f32_16x16x32_bf16(a[1],bw[1][nt],acc,0,0,0);
#pragma unroll
      for (int r=0;r<4;r++){
        float v = acc[r] + bs[nt];
        ssum[nt]+=v; ssq[nt]+=v*v;
        ybuf[(size_t)(R0 + lg*4 + r)*64 + nt*16 + lr] = f2bf(v);
      }
    }
  }
  float* slot = slots + (size_t)(blockIdx.x & 63)*256;
#pragma unroll
  for (int nt=0;nt<4;nt++){
    float s1=ssum[nt], s2=ssq[nt];
    s1 += __shfl_xor(s1,16); s1 += __shfl_xor(s1,32);
    s2 += __shfl_xor(s2,16); s2 += __shfl_xor(s2,32);
    if (lane<16){
      atomicAdd(slot + nt*16+lr, s1);
      atomicAdd(slot + 128 + nt*16+lr, s2);
    }
  }
}

// ---------------------------------------------------------------------------
// K7: layer2 stats pass (affine1+relu on y1, GEMM W2 64x128, stats; no store)
// ---------------------------------------------------------------------------
__global__ __launch_bounds__(256) void gemm2stats_kernel(const unsigned short* __restrict__ ybuf,
    const float* __restrict__ W, const float* __restrict__ bv,
    const float* __restrict__ par1, float* __restrict__ slots){
  const int tid=threadIdx.x, lane=tid&63, w=tid>>6;
  const int lg=lane>>4, lr=lane&15;
  float sc[2][8], sh[2][8];
#pragma unroll
  for (int kc=0;kc<2;kc++){
    int c0=kc*32+lg*8;
#pragma unroll
    for (int j=0;j<8;j++){ sc[kc][j]=par1[c0+j]; sh[kc][j]=par1[128+c0+j]; }
  }
  bf16x8 bw[2][8];
#pragma unroll
  for (int kc=0;kc<2;kc++)
#pragma unroll
    for (int nt=0;nt<8;nt++){
      u16x8 t;
#pragma unroll
      for (int j=0;j<8;j++){
        int k=kc*32+lg*8+j, n=nt*16+lr;
        t[j]=f2bf(W[k*128+n]);
      }
      bw[kc][nt]=__builtin_bit_cast(bf16x8,t);
    }
  float bs[8], ssum[8], ssq[8];
#pragma unroll
  for (int nt=0;nt<8;nt++){ bs[nt]=bv[nt*16+lr]; ssum[nt]=0.f; ssq[nt]=0.f; }
  const int base_row = blockIdx.x*512;
  for (int ti=0;ti<TPW;ti++){
    const int R0 = base_row + (w*TPW+ti)*16;
    const unsigned short* yr = ybuf + (size_t)(R0+lr)*64;
    bf16x8 a[2];
#pragma unroll
    for (int kc=0;kc<2;kc++){
      u16x8 rv = *(const u16x8*)(yr + kc*32 + lg*8);
      u16x8 t;
#pragma unroll
      for (int j=0;j<8;j++){
        float v = bf2f(rv[j]);
        v = fmaxf(fmaf(v, sc[kc][j], sh[kc][j]), 0.f);
        t[j]=f2bf(v);
      }
      a[kc]=__builtin_bit_cast(bf16x8,t);
    }
#pragma unroll
    for (int nt=0;nt<8;nt++){
      f32x4 acc={0,0,0,0};
      acc=__builtin_amdgcn_mfma_f32_16x16x32_bf16(a[0],bw[0][nt],acc,0,0,0);
      acc=__builtin_amdgcn_mfma_f32_16x16x32_bf16(a[1],bw[1][nt],acc,0,0,0);
#pragma unroll
      for (int r=0;r<4;r++){
        float v = acc[r] + bs[nt];
        ssum[nt]+=v; ssq[nt]+=v*v;
      }
    }
  }
  float* slot = slots + (size_t)(blockIdx.x & 63)*256;
#pragma unroll
  for (int nt=0;nt<8;nt++){
    float s1=ssum[nt], s2=ssq[nt];
    s1 += __shfl_xor(s1,16); s1 += __shfl_xor(s1,32);
    s2 += __shfl_xor(s2,16); s2 += __shfl_xor(s2,32);
    if (lane<16){
      atomicAdd(slot + nt*16+lr, s1);
      atomicAdd(slot + 128 + nt*16+lr, s2);
    }
  }
}

// ---------------------------------------------------------------------------
// K8: layer2 recompute + BN2 + relu + max over K -> f_out.
// ---------------------------------------------------------------------------
#define QPW 8
__global__ __launch_bounds__(256) void gemm2max_kernel(const unsigned short* __restrict__ ybuf,
    const float* __restrict__ W, const float* __restrict__ bv,
    const float* __restrict__ par1, const float* __restrict__ par2,
    float* __restrict__ fout){
  const int tid=threadIdx.x, lane=tid&63, w=tid>>6;
  const int lg=lane>>4, lr=lane&15;
  float sc1[2][8], sh1[2][8];
#pragma unroll
  for (int kc=0;kc<2;kc++){
    int c0=kc*32+lg*8;
#pragma unroll
    for (int j=0;j<8;j++){ sc1[kc][j]=par1[c0+j]; sh1[kc][j]=par1[128+c0+j]; }
  }
  float sc2[8], sh2[8], bs[8];
#pragma unroll
  for (int nt=0;nt<8;nt++){
    int n=nt*16+lr;
    sc2[nt]=par2[n]; sh2[nt]=par2[128+n]; bs[nt]=bv[n];
  }
  bf16x8 bw[2][8];
#pragma unroll
  for (int kc=0;kc<2;kc++)
#pragma unroll
    for (int nt=0;nt<8;nt++){
      u16x8 t;
#pragma unroll
      for (int j=0;j<8;j++){
        int k=kc*32+lg*8+j, n=nt*16+lr;
        t[j]=f2bf(W[k*128+n]);
      }
      bw[kc][nt]=__builtin_bit_cast(bf16x8,t);
    }
  const int qbase = blockIdx.x*(4*QPW) + w*QPW;
  for (int qi=0;qi<QPW;qi++){
    const int gq = qbase + qi;
    float qmax[8];
#pragma unroll
    for (int nt=0;nt<8;nt++) qmax[nt]=-1e30f;
#pragma unroll
    for (int half=0; half<2; half++){
      const int R0 = gq*32 + half*16;
      const unsigned short* yr = ybuf + (size_t)(R0+lr)*64;
      bf16x8 a[2];
#pragma unroll
      for (int kc=0;kc<2;kc++){
        u16x8 rv = *(const u16x8*)(yr + kc*32 + lg*8);
        u16x8 t;
#pragma unroll
        for (int j=0;j<8;j++){
          float v = bf2f(rv[j]);
          v = fmaxf(fmaf(v, sc1[kc][j], sh1[kc][j]), 0.f);
          t[j]=f2bf(v);
        }
        a[kc]=__builtin_bit_cast(bf16x8,t);
      }
#pragma unroll
      for (int nt=0;nt<8;nt++){
        f32x4 acc={0,0,0,0};
        acc=__builtin_amdgcn_mfma_f32_16x16x32_bf16(a[0],bw[0][nt],acc,0,0,0);
        acc=__builtin_amdgcn_mfma_f32_16x16x32_bf16(a[1],bw[1][nt],acc,0,0,0);
        float m=-1e30f;
#pragma unroll
        for (int r=0;r<4;r++){
          float v = acc[r] + bs[nt];
          v = fmaxf(fmaf(v, sc2[nt], sh2[nt]), 0.f);
          m = fmaxf(m, v);
        }
        m = fmaxf(m, __shfl_xor(m,16));
        m = fmaxf(m, __shfl_xor(m,32));
        qmax[nt] = fmaxf(qmax[nt], m);
      }
    }
    if (lane<16){
#pragma unroll
      for (int nt=0;nt<8;nt++)
        fout[(size_t)gq*128 + nt*16 + lane] = qmax[nt];
    }
  }
}

// ---------------------------------------------------------------------------
extern "C" void kernel_launch(void* const* d_in, const int* in_sizes, int n_in,
                              void* d_out, int out_size, void* d_ws, size_t ws_size,
                              hipStream_t stream){
  const float* f   = (const float*)d_in[0];
  const float* p   = (const float*)d_in[1];
  const float* W0  = (const float*)d_in[2];
  const float* b0  = (const float*)d_in[3];
  const float* g0  = (const float*)d_in[4];
  const float* be0 = (const float*)d_in[5];
  const float* W1  = (const float*)d_in[6];
  const float* b1  = (const float*)d_in[7];
  const float* g1  = (const float*)d_in[8];
  const float* be1 = (const float*)d_in[9];
  const float* W2  = (const float*)d_in[10];
  const float* b2  = (const float*)d_in[11];
  const float* g2  = (const float*)d_in[12];
  const float* be2 = (const float*)d_in[13];

  float* out = (float*)d_out;
  float* qry = out + (size_t)NB*NS*128;   // second output: qry_pnt

  char* w = (char*)d_ws;
  int* grp = (int*)w;                                             // 2 MB
  unsigned short* ybuf = (unsigned short*)(w + (size_t)2*1024*1024);  // 64 MB
  float* slots = (float*)(w + (size_t)2*1024*1024 + (size_t)NROWS*64*2); // 64 KB
  float* par0 = slots + 64*256;
  float* par1 = par0 + 256;
  float* par2 = par1 + 256;

  fps_kernel<<<NB, FPS_T, 0, stream>>>(p, qry);
  ballq_kernel<<<NB*(NS/8), BQ_T, 0, stream>>>(p, qry, grp);
  zero_slots_kernel<<<64, 256, 0, stream>>>(slots);
  gemm0_kernel<<<NROWS/512, 256, 0, stream>>>(f, p, qry, grp, W0, b0, ybuf, slots);
  finalize_kernel<<<1, 128, 0, stream>>>(slots, g0, be0, par0, 64);
  gemm1_kernel<<<NROWS/512, 256, 0, stream>>>(ybuf, W1, b1, par0, slots);
  finalize_kernel<<<1, 128, 0, stream>>>(slots, g1, be1, par1, 64);
  gemm2stats_kernel<<<NROWS/512, 256, 0, stream>>>(ybuf, W2, b2, par1, slots);
  finalize_kernel<<<1, 128, 0, stream>>>(slots, g2, be2, par2, 128);
  gemm2max_kernel<<<NB*NS/(4*QPW), 256, 0, stream>>>(ybuf, W2, b2, par1, par2, out);
}

// Round 8
// 984.094 us; speedup vs baseline: 5.2446x; 5.2446x over previous
//
#include <hip/hip_runtime.h>

#define NB 16
#define NP 4096
#define CF 64
#define NS 1024
#define NK 32
#define NROWS (NB*NS*NK)   // 524288

typedef float f32x4 __attribute__((ext_vector_type(4)));
typedef __bf16 bf16x8 __attribute__((ext_vector_type(8)));
typedef unsigned short u16x8 __attribute__((ext_vector_type(8)));

__device__ __forceinline__ unsigned short f2bf(float f){
  unsigned u = __float_as_uint(f);
  return (unsigned short)((u + 0x7FFFu + ((u>>16)&1u)) >> 16);
}
__device__ __forceinline__ float bf2f(unsigned short s){
  return __uint_as_float(((unsigned)s)<<16);
}

// DPP-assisted in-row max (xor1,2,4,8), literals required for dpp_ctrl.
__device__ __forceinline__ float dppmax_b1(float x){
  int y=__builtin_amdgcn_update_dpp(0,__float_as_int(x),0xB1,0xF,0xF,true);
  return fmaxf(x,__int_as_float(y));
}
__device__ __forceinline__ float dppmax_4e(float x){
  int y=__builtin_amdgcn_update_dpp(0,__float_as_int(x),0x4E,0xF,0xF,true);
  return fmaxf(x,__int_as_float(y));
}
__device__ __forceinline__ float dppmax_hm(float x){  // row_half_mirror (xor4)
  int y=__builtin_amdgcn_update_dpp(0,__float_as_int(x),0x141,0xF,0xF,true);
  return fmaxf(x,__int_as_float(y));
}
__device__ __forceinline__ float dppmax_m(float x){   // row_mirror (xor8)
  int y=__builtin_amdgcn_update_dpp(0,__float_as_int(x),0x140,0xF,0xF,true);
  return fmaxf(x,__int_as_float(y));
}

__device__ __forceinline__ float4 sel4(bool c, float4 a, float4 b){
  return make_float4(c?a.x:b.x, c?a.y:b.y, c?a.z:b.z, c?a.w:b.w);
}

// ---------------------------------------------------------------------------
// K1: furthest point sampling. One block (256 thr, 4 waves) per batch.
// Bit-exact vs numpy: strict-rounded scalar ops in reference association
// order ((dx*dx+dy*dy)+dz*dz). First-index argmax tie-break:
//   in-thread: serial strict-> scan (keeps lowest j); coords carried as 4
//              SCALARS (bv,wx,wy,wz) — no arrays, no tree copies, no spill
//              (launch_bounds(,1) licenses full per-wave VGPR budget),
//   in-wave  : ballot + ffs keeps lowest lane (lane order == index order),
//   x-wave   : 3-node float4 tournament keeps lower wid on ties.
// No LDS point mirror, no dependent P4[winner] read.
// ---------------------------------------------------------------------------
#define FPS_T 256
__global__ __launch_bounds__(FPS_T, 1) void fps_kernel(const float* __restrict__ p,
                                                       float* __restrict__ qry){
  __shared__ float4 ebuf[2][4];
  const int b = blockIdx.x, tid = threadIdx.x;
  const int lane = tid & 63, wid = tid >> 6;
  const float* pb = p + (size_t)b*NP*3;
  float px[16], py[16], pz[16], dist[16];
#pragma unroll
  for (int g=0; g<4; g++){
    const int i0 = tid*16 + g*4;
    const float* src = pb + (size_t)i0*3;
    f32x4 a = *(const f32x4*)(src);
    f32x4 c = *(const f32x4*)(src+4);
    f32x4 d = *(const f32x4*)(src+8);
    px[g*4+0]=a[0]; py[g*4+0]=a[1]; pz[g*4+0]=a[2];
    px[g*4+1]=a[3]; py[g*4+1]=c[0]; pz[g*4+1]=c[1];
    px[g*4+2]=c[2]; py[g*4+2]=c[3]; pz[g*4+2]=d[0];
    px[g*4+3]=d[1]; py[g*4+3]=d[2]; pz[g*4+3]=d[3];
#pragma unroll
    for (int j=0;j<4;j++) dist[g*4+j]=1e10f;
  }
  float lx=pb[0], ly=pb[1], lz=pb[2];
  for (int t=0;t<NS;t++){
    if (tid==0){
      size_t o=(size_t)(b*NS+t)*3;
      qry[o+0]=lx; qry[o+1]=ly; qry[o+2]=lz;
    }
    float bv=-1.0f, wx=0.f, wy=0.f, wz=0.f;
#pragma unroll
    for (int j=0;j<16;j++){
      float dx=__fsub_rn(px[j],lx), dy=__fsub_rn(py[j],ly), dz=__fsub_rn(pz[j],lz);
      float d=__fadd_rn(__fadd_rn(__fmul_rn(dx,dx),__fmul_rn(dy,dy)),__fmul_rn(dz,dz));
      dist[j]=fminf(dist[j],d);
      if (dist[j]>bv){ bv=dist[j]; wx=px[j]; wy=py[j]; wz=pz[j]; }
    }
    // wave max of bv: DPP butterfly in 16-lane rows, then 4 readlanes+scalar
    float m = bv;
    m = dppmax_b1(m);            // xor 1
    m = dppmax_4e(m);            // xor 2
    m = dppmax_hm(m);            // xor 4
    m = dppmax_m(m);             // xor 8
    unsigned m0 = (unsigned)__builtin_amdgcn_readlane(__float_as_int(m), 0);
    unsigned m1 = (unsigned)__builtin_amdgcn_readlane(__float_as_int(m), 16);
    unsigned m2 = (unsigned)__builtin_amdgcn_readlane(__float_as_int(m), 32);
    unsigned m3 = (unsigned)__builtin_amdgcn_readlane(__float_as_int(m), 48);
    unsigned ma = m0>m1?m0:m1, mb = m2>m3?m2:m3;
    unsigned mu = ma>mb?ma:mb;   // valid: dist >= 0 so u32 compare == f32
    // first lane holding the max (lane order == index order)
    unsigned long long ball = __ballot(__float_as_uint(bv)==mu);
    int srcl = (int)(__ffsll((long long)ball) - 1);
    float cx = __uint_as_float(__builtin_amdgcn_readlane(__float_as_int(wx), srcl));
    float cy = __uint_as_float(__builtin_amdgcn_readlane(__float_as_int(wy), srcl));
    float cz = __uint_as_float(__builtin_amdgcn_readlane(__float_as_int(wz), srcl));
    if (lane==0) ebuf[t&1][wid] = make_float4(cx,cy,cz,__uint_as_float(mu));
    __syncthreads();
    // tournament over 4 wave entries; strict > keeps lower wid on ties
    float4 e0=ebuf[t&1][0], e1=ebuf[t&1][1], e2=ebuf[t&1][2], e3=ebuf[t&1][3];
    float4 a01 = sel4(e1.w>e0.w, e1, e0);
    float4 a23 = sel4(e3.w>e2.w, e3, e2);
    float4 win = sel4(a23.w>a01.w, a23, a01);
    lx=win.x; ly=win.y; lz=win.z;
  }
}

// ---------------------------------------------------------------------------
// K2: ball query, wave-per-query ordered ballot scan.
// ---------------------------------------------------------------------------
#define BQ_T 512
__global__ __launch_bounds__(BQ_T) void ballq_kernel(const float* __restrict__ p,
                                                     const float* __restrict__ qry,
                                                     int* __restrict__ grp){
  __shared__ float PX[NP], PY[NP], PZ[NP];
  const int tid = threadIdx.x, lane = tid & 63, w = tid >> 6;  // 8 waves
  const int b  = blockIdx.x >> 7;          // 128 blocks per batch
  const int s0 = (blockIdx.x & 127) * 8;   // 8 queries per block
  const float* pb = p + (size_t)b*NP*3;
  for (int i = tid; i < NP; i += BQ_T){
    PX[i]=pb[i*3+0]; PY[i]=pb[i*3+1]; PZ[i]=pb[i*3+2];
  }
  __syncthreads();
  const int s = s0 + w;
  const float* q = qry + (size_t)(b*NS+s)*3;
  const float qx=q[0], qy=q[1], qz=q[2];
  int* out = grp + (size_t)(b*NS+s)*NK;
  const float RR = (float)(0.2*0.2);
  int cum = 0, first = 0;
  for (int j=0;j<NP/64;j++){
    const int idx = j*64 + lane;
    float dx=__fsub_rn(qx,PX[idx]), dy=__fsub_rn(qy,PY[idx]), dz=__fsub_rn(qz,PZ[idx]);
    float sq=__fadd_rn(__fadd_rn(__fmul_rn(dx,dx),__fmul_rn(dy,dy)),__fmul_rn(dz,dz));
    const bool in_r = (sq <= RR);
    unsigned long long ball = __ballot(in_r);
    if (ball){
      if (cum == 0) first = j*64 + (int)__builtin_ctzll(ball);
      int below = __builtin_amdgcn_mbcnt_hi((unsigned)(ball>>32),
                    __builtin_amdgcn_mbcnt_lo((unsigned)ball, 0));
      int pos = cum + below;
      if (in_r && pos < NK) out[pos] = idx;
      cum += (int)__popcll(ball);
      if (cum >= NK) break;
    }
  }
  const int cnt = cum < NK ? cum : NK;
  if (lane >= cnt && lane < NK) out[lane] = first;
}

// ---------------------------------------------------------------------------
// K3: zero stats slots (first-call 0xAA poison; finalize re-zeros afterwards)
// ---------------------------------------------------------------------------
__global__ void zero_slots_kernel(float* __restrict__ slots){
  int i = blockIdx.x*256 + threadIdx.x;
  if (i < 64*256) slots[i]=0.0f;
}

// ---------------------------------------------------------------------------
// K4: fused gather + layer0 GEMM (K=67 padded to 96) + pre-BN stats.
// ---------------------------------------------------------------------------
#define TPW 8
__global__ __launch_bounds__(256) void gemm0_kernel(const float* __restrict__ f,
    const float* __restrict__ p, const float* __restrict__ qry,
    const int* __restrict__ grp, const float* __restrict__ W0,
    const float* __restrict__ b0, unsigned short* __restrict__ ybuf,
    float* __restrict__ slots){
  const int tid=threadIdx.x, lane=tid&63, w=tid>>6;
  const int lg=lane>>4, lr=lane&15;
  bf16x8 bw[3][4];
#pragma unroll
  for (int kc=0;kc<3;kc++)
#pragma unroll
    for (int nt=0;nt<4;nt++){
      u16x8 t;
#pragma unroll
      for (int j=0;j<8;j++){
        int k = kc*32 + lg*8 + j, n = nt*16 + lr;
        float v = (k<67) ? W0[k*64+n] : 0.0f;
        t[j]=f2bf(v);
      }
      bw[kc][nt]=__builtin_bit_cast(bf16x8,t);
    }
  float bs[4];
#pragma unroll
  for (int nt=0;nt<4;nt++) bs[nt]=b0[nt*16+lr];
  float ssum[4]={0,0,0,0}, ssq[4]={0,0,0,0};
  const int base_row = blockIdx.x*512;
  const int b = base_row / (NS*NK);
  for (int ti=0;ti<TPW;ti++){
    const int R0 = base_row + (w*TPW+ti)*16;
    const int Ra = R0 + lr;
    const int idxp = grp[Ra];
    const float* frow = f + ((size_t)(b*NP+idxp))*64;
    f32x4 u0=*(const f32x4*)(frow + lg*8);
    f32x4 u1=*(const f32x4*)(frow + lg*8 + 4);
    f32x4 u2=*(const f32x4*)(frow + 32 + lg*8);
    f32x4 u3=*(const f32x4*)(frow + 36 + lg*8);
    u16x8 t0, t1;
#pragma unroll
    for (int j=0;j<4;j++){
      t0[j]=f2bf(u0[j]); t0[4+j]=f2bf(u1[j]);
      t1[j]=f2bf(u2[j]); t1[4+j]=f2bf(u3[j]);
    }
    u16x8 t2={0,0,0,0,0,0,0,0};
    if (lg==0){
      const int qidx = Ra >> 5;  // b*NS + s
      const float* pp = p + ((size_t)(b*NP+idxp))*3;
      const float* qq = qry + (size_t)qidx*3;
      t2[0]=f2bf(__fsub_rn(pp[0],qq[0]));
      t2[1]=f2bf(__fsub_rn(pp[1],qq[1]));
      t2[2]=f2bf(__fsub_rn(pp[2],qq[2]));
    }
    bf16x8 a0=__builtin_bit_cast(bf16x8,t0);
    bf16x8 a1=__builtin_bit_cast(bf16x8,t1);
    bf16x8 a2=__builtin_bit_cast(bf16x8,t2);
#pragma unroll
    for (int nt=0;nt<4;nt++){
      f32x4 acc={0,0,0,0};
      acc=__builtin_amdgcn_mfma_f32_16x16x32_bf16(a0,bw[0][nt],acc,0,0,0);
      acc=__builtin_amdgcn_mfma_f32_16x16x32_bf16(a1,bw[1][nt],acc,0,0,0);
      acc=__builtin_amdgcn_mfma_f32_16x16x32_bf16(a2,bw[2][nt],acc,0,0,0);
#pragma unroll
      for (int r=0;r<4;r++){
        float v = acc[r] + bs[nt];
        ssum[nt]+=v; ssq[nt]+=v*v;
        ybuf[(size_t)(R0 + lg*4 + r)*64 + nt*16 + lr] = f2bf(v);
      }
    }
  }
  float* slot = slots + (size_t)(blockIdx.x & 63)*256;
#pragma unroll
  for (int nt=0;nt<4;nt++){
    float s1=ssum[nt], s2=ssq[nt];
    s1 += __shfl_xor(s1,16); s1 += __shfl_xor(s1,32);
    s2 += __shfl_xor(s2,16); s2 += __shfl_xor(s2,32);
    if (lane<16){
      atomicAdd(slot + nt*16+lr, s1);
      atomicAdd(slot + 128 + nt*16+lr, s2);
    }
  }
}

// ---------------------------------------------------------------------------
// K5: finalize BN params for a layer; also re-zero slots for the next layer.
// ---------------------------------------------------------------------------
__global__ void finalize_kernel(float* __restrict__ slots,
                                const float* __restrict__ gamma,
                                const float* __restrict__ beta,
                                float* __restrict__ par, int Cc){
  const int c = threadIdx.x;  // 128 threads
  float s1=0.f, s2=0.f;
  for (int i=0;i<64;i++){ s1+=slots[i*256+c]; s2+=slots[i*256+128+c]; }
  const float invM = 1.0f/(float)NROWS;
  if (c<Cc){
    float mean = s1*invM;
    float var  = s2*invM - mean*mean;
    float scale = gamma[c]/sqrtf(var + 1e-5f);
    par[c]      = scale;
    par[128+c]  = beta[c] - mean*scale;
  }
  for (int i=0;i<64;i++){ slots[i*256+c]=0.f; slots[i*256+128+c]=0.f; }
}

// ---------------------------------------------------------------------------
// K6: layer1 = affine0+relu on y0, GEMM with W1 (64x64), stats; in-place y0->y1
// ---------------------------------------------------------------------------
__global__ __launch_bounds__(256) void gemm1_kernel(unsigned short* __restrict__ ybuf,
    const float* __restrict__ W, const float* __restrict__ bv,
    const float* __restrict__ par0, float* __restrict__ slots){
  const int tid=threadIdx.x, lane=tid&63, w=tid>>6;
  const int lg=lane>>4, lr=lane&15;
  float sc[2][8], sh[2][8];
#pragma unroll
  for (int kc=0;kc<2;kc++){
    int c0=kc*32+lg*8;
#pragma unroll
    for (int j=0;j<8;j++){ sc[kc][j]=par0[c0+j]; sh[kc][j]=par0[128+c0+j]; }
  }
  bf16x8 bw[2][4];
#pragma unroll
  for (int kc=0;kc<2;kc++)
#pragma unroll
    for (int nt=0;nt<4;nt++){
      u16x8 t;
#pragma unroll
      for (int j=0;j<8;j++){
        int k=kc*32+lg*8+j, n=nt*16+lr;
        t[j]=f2bf(W[k*64+n]);
      }
      bw[kc][nt]=__builtin_bit_cast(bf16x8,t);
    }
  float bs[4];
#pragma unroll
  for (int nt=0;nt<4;nt++) bs[nt]=bv[nt*16+lr];
  float ssum[4]={0,0,0,0}, ssq[4]={0,0,0,0};
  const int base_row = blockIdx.x*512;
  for (int ti=0;ti<TPW;ti++){
    const int R0 = base_row + (w*TPW+ti)*16;
    const unsigned short* yr = ybuf + (size_t)(R0+lr)*64;
    bf16x8 a[2];
#pragma unroll
    for (int kc=0;kc<2;kc++){
      u16x8 rv = *(const u16x8*)(yr + kc*32 + lg*8);
      u16x8 t;
#pragma unroll
      for (int j=0;j<8;j++){
        float v = bf2f(rv[j]);
        v = fmaxf(fmaf(v, sc[kc][j], sh[kc][j]), 0.f);
        t[j]=f2bf(v);
      }
      a[kc]=__builtin_bit_cast(bf16x8,t);
    }
#pragma unroll
    for (int nt=0;nt<4;nt++){
      f32x4 acc={0,0,0,0};
      acc=__builtin_amdgcn_mfma_f32_16x16x32_bf16(a[0],bw[0][nt],acc,0,0,0);
      acc=__builtin_amdgcn_mfma_f32_16x16x32_bf16(a[1],bw[1][nt],acc,0,0,0);
#pragma unroll
      for (int r=0;r<4;r++){
        float v = acc[r] + bs[nt];
        ssum[nt]+=v; ssq[nt]+=v*v;
        ybuf[(size_t)(R0 + lg*4 + r)*64 + nt*16 + lr] = f2bf(v);
      }
    }
  }
  float* slot = slots + (size_t)(blockIdx.x & 63)*256;
#pragma unroll
  for (int nt=0;nt<4;nt++){
    float s1=ssum[nt], s2=ssq[nt];
    s1 += __shfl_xor(s1,16); s1 += __shfl_xor(s1,32);
    s2 += __shfl_xor(s2,16); s2 += __shfl_xor(s2,32);
    if (lane<16){
      atomicAdd(slot + nt*16+lr, s1);
      atomicAdd(slot + 128 + nt*16+lr, s2);
    }
  }
}

// ---------------------------------------------------------------------------
// K7a (fused path): layer2 GEMM once -> stats2 + per-query max AND min of raw
// z2. max/min commute with the monotone BN2+relu applied later (scale>0 uses
// max, scale<0 uses min; correctly-rounded fmaf is monotone in z).
// ---------------------------------------------------------------------------
__global__ __launch_bounds__(256) void gemm2fused_kernel(const unsigned short* __restrict__ ybuf,
    const float* __restrict__ W, const float* __restrict__ bv,
    const float* __restrict__ par1, float* __restrict__ slots,
    float* __restrict__ zmax, float* __restrict__ zmin){
  const int tid=threadIdx.x, lane=tid&63, w=tid>>6;
  const int lg=lane>>4, lr=lane&15;
  float sc[2][8], sh[2][8];
#pragma unroll
  for (int kc=0;kc<2;kc++){
    int c0=kc*32+lg*8;
#pragma unroll
    for (int j=0;j<8;j++){ sc[kc][j]=par1[c0+j]; sh[kc][j]=par1[128+c0+j]; }
  }
  bf16x8 bw[2][8];
#pragma unroll
  for (int kc=0;kc<2;kc++)
#pragma unroll
    for (int nt=0;nt<8;nt++){
      u16x8 t;
#pragma unroll
      for (int j=0;j<8;j++){
        int k=kc*32+lg*8+j, n=nt*16+lr;
        t[j]=f2bf(W[k*128+n]);
      }
      bw[kc][nt]=__builtin_bit_cast(bf16x8,t);
    }
  float bs[8], ssum[8], ssq[8], qmax[8], qmin[8];
#pragma unroll
  for (int nt=0;nt<8;nt++){
    bs[nt]=bv[nt*16+lr]; ssum[nt]=0.f; ssq[nt]=0.f;
    qmax[nt]=-3e38f; qmin[nt]=3e38f;
  }
  const int base_row = blockIdx.x*512;
  for (int ti=0;ti<TPW;ti++){
    const int R0 = base_row + (w*TPW+ti)*16;
    const unsigned short* yr = ybuf + (size_t)(R0+lr)*64;
    bf16x8 a[2];
#pragma unroll
    for (int kc=0;kc<2;kc++){
      u16x8 rv = *(const u16x8*)(yr + kc*32 + lg*8);
      u16x8 t;
#pragma unroll
      for (int j=0;j<8;j++){
        float v = bf2f(rv[j]);
        v = fmaxf(fmaf(v, sc[kc][j], sh[kc][j]), 0.f);
        t[j]=f2bf(v);
      }
      a[kc]=__builtin_bit_cast(bf16x8,t);
    }
#pragma unroll
    for (int nt=0;nt<8;nt++){
      f32x4 acc={0,0,0,0};
      acc=__builtin_amdgcn_mfma_f32_16x16x32_bf16(a[0],bw[0][nt],acc,0,0,0);
      acc=__builtin_amdgcn_mfma_f32_16x16x32_bf16(a[1],bw[1][nt],acc,0,0,0);
#pragma unroll
      for (int r=0;r<4;r++){
        float v = acc[r] + bs[nt];
        ssum[nt]+=v; ssq[nt]+=v*v;
        qmax[nt]=fmaxf(qmax[nt],v); qmin[nt]=fminf(qmin[nt],v);
      }
    }
    if (ti & 1){
      const int q = R0 >> 5;   // rows [32q,32q+32) covered by tiles ti-1,ti
#pragma unroll
      for (int nt=0;nt<8;nt++){
        float mx=qmax[nt], mn=qmin[nt];
        mx = fmaxf(mx, __shfl_xor(mx,16)); mx = fmaxf(mx, __shfl_xor(mx,32));
        mn = fminf(mn, __shfl_xor(mn,16)); mn = fminf(mn, __shfl_xor(mn,32));
        if (lane<16){
          zmax[(size_t)q*128 + nt*16 + lane] = mx;
          zmin[(size_t)q*128 + nt*16 + lane] = mn;
        }
        qmax[nt]=-3e38f; qmin[nt]=3e38f;
      }
    }
  }
  float* slot = slots + (size_t)(blockIdx.x & 63)*256;
#pragma unroll
  for (int nt=0;nt<8;nt++){
    float s1=ssum[nt], s2=ssq[nt];
    s1 += __shfl_xor(s1,16); s1 += __shfl_xor(s1,32);
    s2 += __shfl_xor(s2,16); s2 += __shfl_xor(s2,32);
    if (lane<16){
      atomicAdd(slot + nt*16+lr, s1);
      atomicAdd(slot + 128 + nt*16+lr, s2);
    }
  }
}

// K7b (fused path): apply BN2+relu to the per-query extremum.
__global__ void bn2max_kernel(const float* __restrict__ zmax,
                              const float* __restrict__ zmin,
                              const float* __restrict__ par2,
                              float* __restrict__ fout){
  int idx = blockIdx.x*256 + threadIdx.x;     // NB*NS*128 = 2M
  if (idx < NB*NS*128){
    int c = idx & 127;
    float scale = par2[c], shift = par2[128+c];
    float z = (scale > 0.f) ? zmax[idx] : zmin[idx];
    fout[idx] = fmaxf(fmaf(z, scale, shift), 0.f);
  }
}

// ---------------------------------------------------------------------------
// K7/K8 (fallback path, used when ws too small): stats pass + recompute+max.
// ---------------------------------------------------------------------------
__global__ __launch_bounds__(256) void gemm2stats_kernel(const unsigned short* __restrict__ ybuf,
    const float* __restrict__ W, const float* __restrict__ bv,
    const float* __restrict__ par1, float* __restrict__ slots){
  const int tid=threadIdx.x, lane=tid&63, w=tid>>6;
  const int lg=lane>>4, lr=lane&15;
  float sc[2][8], sh[2][8];
#pragma unroll
  for (int kc=0;kc<2;kc++){
    int c0=kc*32+lg*8;
#pragma unroll
    for (int j=0;j<8;j++){ sc[kc][j]=par1[c0+j]; sh[kc][j]=par1[128+c0+j]; }
  }
  bf16x8 bw[2][8];
#pragma unroll
  for (int kc=0;kc<2;kc++)
#pragma unroll
    for (int nt=0;nt<8;nt++){
      u16x8 t;
#pragma unroll
      for (int j=0;j<8;j++){
        int k=kc*32+lg*8+j, n=nt*16+lr;
        t[j]=f2bf(W[k*128+n]);
      }
      bw[kc][nt]=__builtin_bit_cast(bf16x8,t);
    }
  float bs[8], ssum[8], ssq[8];
#pragma unroll
  for (int nt=0;nt<8;nt++){ bs[nt]=bv[nt*16+lr]; ssum[nt]=0.f; ssq[nt]=0.f; }
  const int base_row = blockIdx.x*512;
  for (int ti=0;ti<TPW;ti++){
    const int R0 = base_row + (w*TPW+ti)*16;
    const unsigned short* yr = ybuf + (size_t)(R0+lr)*64;
    bf16x8 a[2];
#pragma unroll
    for (int kc=0;kc<2;kc++){
      u16x8 rv = *(const u16x8*)(yr + kc*32 + lg*8);
      u16x8 t;
#pragma unroll
      for (int j=0;j<8;j++){
        float v = bf2f(rv[j]);
        v = fmaxf(fmaf(v, sc[kc][j], sh[kc][j]), 0.f);
        t[j]=f2bf(v);
      }
      a[kc]=__builtin_bit_cast(bf16x8,t);
    }
#pragma unroll
    for (int nt=0;nt<8;nt++){
      f32x4 acc={0,0,0,0};
      acc=__builtin_amdgcn_mfma_f32_16x16x32_bf16(a[0],bw[0][nt],acc,0,0,0);
      acc=__builtin_amdgcn_mfma_f32_16x16x32_bf16(a[1],bw[1][nt],acc,0,0,0);
#pragma unroll
      for (int r=0;r<4;r++){
        float v = acc[r] + bs[nt];
        ssum[nt]+=v; ssq[nt]+=v*v;
      }
    }
  }
  float* slot = slots + (size_t)(blockIdx.x & 63)*256;
#pragma unroll
  for (int nt=0;nt<8;nt++){
    float s1=ssum[nt], s2=ssq[nt];
    s1 += __shfl_xor(s1,16); s1 += __shfl_xor(s1,32);
    s2 += __shfl_xor(s2,16); s2 += __shfl_xor(s2,32);
    if (lane<16){
      atomicAdd(slot + nt*16+lr, s1);
      atomicAdd(slot + 128 + nt*16+lr, s2);
    }
  }
}

#define QPW 8
__global__ __launch_bounds__(256) void gemm2max_kernel(const unsigned short* __restrict__ ybuf,
    const float* __restrict__ W, const float* __restrict__ bv,
    const float* __restrict__ par1, const float* __restrict__ par2,
    float* __restrict__ fout){
  const int tid=threadIdx.x, lane=tid&63, w=tid>>6;
  const int lg=lane>>4, lr=lane&15;
  float sc1[2][8], sh1[2][8];
#pragma unroll
  for (int kc=0;kc<2;kc++){
    int c0=kc*32+lg*8;
#pragma unroll
    for (int j=0;j<8;j++){ sc1[kc][j]=par1[c0+j]; sh1[kc][j]=par1[128+c0+j]; }
  }
  float sc2[8], sh2[8], bs[8];
#pragma unroll
  for (int nt=0;nt<8;nt++){
    int n=nt*16+lr;
    sc2[nt]=par2[n]; sh2[nt]=par2[128+n]; bs[nt]=bv[n];
  }
  bf16x8 bw[2][8];
#pragma unroll
  for (int kc=0;kc<2;kc++)
#pragma unroll
    for (int nt=0;nt<8;nt++){
      u16x8 t;
#pragma unroll
      for (int j=0;j<8;j++){
        int k=kc*32+lg*8+j, n=nt*16+lr;
        t[j]=f2bf(W[k*128+n]);
      }
      bw[kc][nt]=__builtin_bit_cast(bf16x8,t);
    }
  const int qbase = blockIdx.x*(4*QPW) + w*QPW;
  for (int qi=0;qi<QPW;qi++){
    const int gq = qbase + qi;
    float qmax[8];
#pragma unroll
    for (int nt=0;nt<8;nt++) qmax[nt]=-1e30f;
#pragma unroll
    for (int half=0; half<2; half++){
      const int R0 = gq*32 + half*16;
      const unsigned short* yr = ybuf + (size_t)(R0+lr)*64;
      bf16x8 a[2];
#pragma unroll
      for (int kc=0;kc<2;kc++){
        u16x8 rv = *(const u16x8*)(yr + kc*32 + lg*8);
        u16x8 t;
#pragma unroll
        for (int j=0;j<8;j++){
          float v = bf2f(rv[j]);
          v = fmaxf(fmaf(v, sc1[kc][j], sh1[kc][j]), 0.f);
          t[j]=f2bf(v);
        }
        a[kc]=__builtin_bit_cast(bf16x8,t);
      }
#pragma unroll
      for (int nt=0;nt<8;nt++){
        f32x4 acc={0,0,0,0};
        acc=__builtin_amdgcn_mfma_f32_16x16x32_bf16(a[0],bw[0][nt],acc,0,0,0);
        acc=__builtin_amdgcn_mfma_f32_16x16x32_bf16(a[1],bw[1][nt],acc,0,0,0);
        float m=-1e30f;
#pragma unroll
        for (int r=0;r<4;r++){
          float v = acc[r] + bs[nt];
          v = fmaxf(fmaf(v, sc2[nt], sh2[nt]), 0.f);
          m = fmaxf(m, v);
        }
        m = fmaxf(m, __shfl_xor(m,16));
        m = fmaxf(m, __shfl_xor(m,32));
        qmax[nt] = fmaxf(qmax[nt], m);
      }
    }
    if (lane<16){
#pragma unroll
      for (int nt=0;nt<8;nt++)
        fout[(size_t)gq*128 + nt*16 + lane] = qmax[nt];
    }
  }
}

// ---------------------------------------------------------------------------
extern "C" void kernel_launch(void* const* d_in, const int* in_sizes, int n_in,
                              void* d_out, int out_size, void* d_ws, size_t ws_size,
                              hipStream_t stream){
  const float* f   = (const float*)d_in[0];
  const float* p   = (const float*)d_in[1];
  const float* W0  = (const float*)d_in[2];
  const float* b0  = (const float*)d_in[3];
  const float* g0  = (const float*)d_in[4];
  const float* be0 = (const float*)d_in[5];
  const float* W1  = (const float*)d_in[6];
  const float* b1  = (const float*)d_in[7];
  const float* g1  = (const float*)d_in[8];
  const float* be1 = (const float*)d_in[9];
  const float* W2  = (const float*)d_in[10];
  const float* b2  = (const float*)d_in[11];
  const float* g2  = (const float*)d_in[12];
  const float* be2 = (const float*)d_in[13];

  float* out = (float*)d_out;
  float* qry = out + (size_t)NB*NS*128;   // second output: qry_pnt

  char* w = (char*)d_ws;
  const size_t off_ybuf  = (size_t)2*1024*1024;
  const size_t off_slots = off_ybuf + (size_t)NROWS*64*2;
  const size_t off_par   = off_slots + (size_t)64*256*4;
  const size_t off_zmm   = (off_par + 3*256*4 + 1023) & ~(size_t)1023;
  const size_t need_fused = off_zmm + (size_t)NB*NS*128*2*4;

  int* grp = (int*)w;
  unsigned short* ybuf = (unsigned short*)(w + off_ybuf);
  float* slots = (float*)(w + off_slots);
  float* par0 = (float*)(w + off_par);
  float* par1 = par0 + 256;
  float* par2 = par1 + 256;
  float* zmax = (float*)(w + off_zmm);
  float* zmin = zmax + (size_t)NB*NS*128;

  fps_kernel<<<NB, FPS_T, 0, stream>>>(p, qry);
  ballq_kernel<<<NB*(NS/8), BQ_T, 0, stream>>>(p, qry, grp);
  zero_slots_kernel<<<64, 256, 0, stream>>>(slots);
  gemm0_kernel<<<NROWS/512, 256, 0, stream>>>(f, p, qry, grp, W0, b0, ybuf, slots);
  finalize_kernel<<<1, 128, 0, stream>>>(slots, g0, be0, par0, 64);
  gemm1_kernel<<<NROWS/512, 256, 0, stream>>>(ybuf, W1, b1, par0, slots);
  finalize_kernel<<<1, 128, 0, stream>>>(slots, g1, be1, par1, 64);
  if (ws_size >= need_fused){
    gemm2fused_kernel<<<NROWS/512, 256, 0, stream>>>(ybuf, W2, b2, par1, slots, zmax, zmin);
    finalize_kernel<<<1, 128, 0, stream>>>(slots, g2, be2, par2, 128);
    bn2max_kernel<<<(NB*NS*128)/256, 256, 0, stream>>>(zmax, zmin, par2, out);
  } else {
    gemm2stats_kernel<<<NROWS/512, 256, 0, stream>>>(ybuf, W2, b2, par1, slots);
    finalize_kernel<<<1, 128, 0, stream>>>(slots, g2, be2, par2, 128);
    gemm2max_kernel<<<NB*NS/(4*QPW), 256, 0, stream>>>(ybuf, W2, b2, par1, par2, out);
  }
}

// Round 9
// 718.163 us; speedup vs baseline: 7.1867x; 1.3703x over previous
//
#include <hip/hip_runtime.h>

#define NB 16
#define NP 4096
#define CF 64
#define NS 1024
#define NK 32
#define NROWS (NB*NS*NK)   // 524288

typedef float f32x4 __attribute__((ext_vector_type(4)));
typedef __bf16 bf16x8 __attribute__((ext_vector_type(8)));
typedef unsigned short u16x8 __attribute__((ext_vector_type(8)));

__device__ __forceinline__ unsigned short f2bf(float f){
  unsigned u = __float_as_uint(f);
  return (unsigned short)((u + 0x7FFFu + ((u>>16)&1u)) >> 16);
}
__device__ __forceinline__ float bf2f(unsigned short s){
  return __uint_as_float(((unsigned)s)<<16);
}

// DPP-assisted in-row max (xor1,2,4,8), literals required for dpp_ctrl.
__device__ __forceinline__ float dppmax_b1(float x){
  int y=__builtin_amdgcn_update_dpp(0,__float_as_int(x),0xB1,0xF,0xF,true);
  return fmaxf(x,__int_as_float(y));
}
__device__ __forceinline__ float dppmax_4e(float x){
  int y=__builtin_amdgcn_update_dpp(0,__float_as_int(x),0x4E,0xF,0xF,true);
  return fmaxf(x,__int_as_float(y));
}
__device__ __forceinline__ float dppmax_hm(float x){  // row_half_mirror (xor4)
  int y=__builtin_amdgcn_update_dpp(0,__float_as_int(x),0x141,0xF,0xF,true);
  return fmaxf(x,__int_as_float(y));
}
__device__ __forceinline__ float dppmax_m(float x){   // row_mirror (xor8)
  int y=__builtin_amdgcn_update_dpp(0,__float_as_int(x),0x140,0xF,0xF,true);
  return fmaxf(x,__int_as_float(y));
}

// ---------------------------------------------------------------------------
// K1: furthest point sampling — EXACT round-3 version (measured 570us,
// VGPR 88 = point arrays resident in registers; do not perturb).
// One block (256 thr, 4 waves) per batch. Bit-exact vs numpy: strict-rounded
// ops in reference association order, first-index argmax tie-break (strict >
// within thread, lowest-lane ballot within wave, packed u64 key with ~idx
// across waves). Wave reduce = 4 DPP steps + readlane x4 + scalar max (dists
// >= 0 so u32 bit compare == float compare). Single barrier per iteration
// via double-buffered key array.
// ---------------------------------------------------------------------------
#define FPS_T 256
#define FPS_PT (NP/FPS_T)   // 16 points per thread
__global__ __launch_bounds__(FPS_T) void fps_kernel(const float* __restrict__ p,
                                                    float* __restrict__ qry){
  __shared__ float4 P4[NP];                    // 64 KB, padded xyz
  __shared__ unsigned long long warr[2][4];
  const int b = blockIdx.x, tid = threadIdx.x;
  const int lane = tid & 63, wid = tid >> 6;
  const float* pb = p + (size_t)b*NP*3;
  float px[FPS_PT], py[FPS_PT], pz[FPS_PT], dist[FPS_PT];
#pragma unroll
  for (int g=0; g<4; g++){
    const int i0 = tid*FPS_PT + g*4;
    const float* src = pb + (size_t)i0*3;
    f32x4 a = *(const f32x4*)(src);
    f32x4 c = *(const f32x4*)(src+4);
    f32x4 d = *(const f32x4*)(src+8);
    px[g*4+0]=a[0]; py[g*4+0]=a[1]; pz[g*4+0]=a[2];
    px[g*4+1]=a[3]; py[g*4+1]=c[0]; pz[g*4+1]=c[1];
    px[g*4+2]=c[2]; py[g*4+2]=c[3]; pz[g*4+2]=d[0];
    px[g*4+3]=d[1]; py[g*4+3]=d[2]; pz[g*4+3]=d[3];
#pragma unroll
    for (int j=0;j<4;j++){
      P4[i0+j]=make_float4(px[g*4+j],py[g*4+j],pz[g*4+j],0.f);
      dist[g*4+j]=1e10f;
    }
  }
  __syncthreads();
  float4 lp0 = P4[0];
  float lx=lp0.x, ly=lp0.y, lz=lp0.z;
  for (int t=0;t<NS;t++){
    if (tid==0){
      size_t o=(size_t)(b*NS+t)*3;
      qry[o+0]=lx; qry[o+1]=ly; qry[o+2]=lz;
    }
    float bv=-1.0f; int bi=0;
#pragma unroll
    for (int j=0;j<FPS_PT;j++){
      float dx=__fsub_rn(px[j],lx), dy=__fsub_rn(py[j],ly), dz=__fsub_rn(pz[j],lz);
      float d=__fadd_rn(__fadd_rn(__fmul_rn(dx,dx),__fmul_rn(dy,dy)),__fmul_rn(dz,dz));
      dist[j]=fminf(dist[j],d);
      if (dist[j]>bv){ bv=dist[j]; bi=j; }
    }
    const int gbi = tid*FPS_PT + bi;
    // wave max via DPP butterfly within 16-lane rows...
    float m = bv;
    m = dppmax_b1(m);            // xor 1
    m = dppmax_4e(m);            // xor 2
    m = dppmax_hm(m);            // xor 4
    m = dppmax_m(m);             // xor 8
    // ...then 4 readlanes + scalar u32 max (valid: dist bits monotone, >=0)
    unsigned m0 = (unsigned)__builtin_amdgcn_readlane(__float_as_int(m), 0);
    unsigned m1 = (unsigned)__builtin_amdgcn_readlane(__float_as_int(m), 16);
    unsigned m2 = (unsigned)__builtin_amdgcn_readlane(__float_as_int(m), 32);
    unsigned m3 = (unsigned)__builtin_amdgcn_readlane(__float_as_int(m), 48);
    unsigned ma = m0>m1?m0:m1, mb = m2>m3?m2:m3;
    unsigned mu = ma>mb?ma:mb;
    // first lane holding the max (lane order == index order)
    unsigned long long ball = __ballot(__float_as_uint(bv)==mu);
    int srcl = (int)(__ffsll((long long)ball) - 1);
    int widx = __builtin_amdgcn_readlane(gbi, srcl);
    if (lane==0)
      warr[t&1][wid] = ((unsigned long long)mu<<32)
                     | (unsigned)(0xFFFFFFFFu-(unsigned)widx);
    __syncthreads();
    unsigned long long k0=warr[t&1][0], k1=warr[t&1][1],
                       k2=warr[t&1][2], k3=warr[t&1][3];
    unsigned long long ka = k0>k1?k0:k1, kb = k2>k3?k2:k3;
    unsigned long long bk = ka>kb?ka:kb;
    const int winner = (int)(0xFFFFFFFFu-(unsigned)(bk & 0xFFFFFFFFull));
    float4 lp = P4[winner];
    lx=lp.x; ly=lp.y; lz=lp.z;
  }
}

// ---------------------------------------------------------------------------
// K2: ball query, wave-per-query ordered ballot scan.
// ---------------------------------------------------------------------------
#define BQ_T 512
__global__ __launch_bounds__(BQ_T) void ballq_kernel(const float* __restrict__ p,
                                                     const float* __restrict__ qry,
                                                     int* __restrict__ grp){
  __shared__ float PX[NP], PY[NP], PZ[NP];
  const int tid = threadIdx.x, lane = tid & 63, w = tid >> 6;  // 8 waves
  const int b  = blockIdx.x >> 7;          // 128 blocks per batch
  const int s0 = (blockIdx.x & 127) * 8;   // 8 queries per block
  const float* pb = p + (size_t)b*NP*3;
  for (int i = tid; i < NP; i += BQ_T){
    PX[i]=pb[i*3+0]; PY[i]=pb[i*3+1]; PZ[i]=pb[i*3+2];
  }
  __syncthreads();
  const int s = s0 + w;
  const float* q = qry + (size_t)(b*NS+s)*3;
  const float qx=q[0], qy=q[1], qz=q[2];
  int* out = grp + (size_t)(b*NS+s)*NK;
  const float RR = (float)(0.2*0.2);
  int cum = 0, first = 0;
  for (int j=0;j<NP/64;j++){
    const int idx = j*64 + lane;
    float dx=__fsub_rn(qx,PX[idx]), dy=__fsub_rn(qy,PY[idx]), dz=__fsub_rn(qz,PZ[idx]);
    float sq=__fadd_rn(__fadd_rn(__fmul_rn(dx,dx),__fmul_rn(dy,dy)),__fmul_rn(dz,dz));
    const bool in_r = (sq <= RR);
    unsigned long long ball = __ballot(in_r);
    if (ball){
      if (cum == 0) first = j*64 + (int)__builtin_ctzll(ball);
      int below = __builtin_amdgcn_mbcnt_hi((unsigned)(ball>>32),
                    __builtin_amdgcn_mbcnt_lo((unsigned)ball, 0));
      int pos = cum + below;
      if (in_r && pos < NK) out[pos] = idx;
      cum += (int)__popcll(ball);
      if (cum >= NK) break;
    }
  }
  const int cnt = cum < NK ? cum : NK;
  if (lane >= cnt && lane < NK) out[lane] = first;
}

// ---------------------------------------------------------------------------
// K3: zero stats slots (first-call 0xAA poison; finalize re-zeros afterwards)
// ---------------------------------------------------------------------------
__global__ void zero_slots_kernel(float* __restrict__ slots){
  int i = blockIdx.x*256 + threadIdx.x;
  if (i < 64*256) slots[i]=0.0f;
}

// ---------------------------------------------------------------------------
// K4: fused gather + layer0 GEMM (K=67 padded to 96) + pre-BN stats.
// ---------------------------------------------------------------------------
#define TPW 8
__global__ __launch_bounds__(256) void gemm0_kernel(const float* __restrict__ f,
    const float* __restrict__ p, const float* __restrict__ qry,
    const int* __restrict__ grp, const float* __restrict__ W0,
    const float* __restrict__ b0, unsigned short* __restrict__ ybuf,
    float* __restrict__ slots){
  const int tid=threadIdx.x, lane=tid&63, w=tid>>6;
  const int lg=lane>>4, lr=lane&15;
  bf16x8 bw[3][4];
#pragma unroll
  for (int kc=0;kc<3;kc++)
#pragma unroll
    for (int nt=0;nt<4;nt++){
      u16x8 t;
#pragma unroll
      for (int j=0;j<8;j++){
        int k = kc*32 + lg*8 + j, n = nt*16 + lr;
        float v = (k<67) ? W0[k*64+n] : 0.0f;
        t[j]=f2bf(v);
      }
      bw[kc][nt]=__builtin_bit_cast(bf16x8,t);
    }
  float bs[4];
#pragma unroll
  for (int nt=0;nt<4;nt++) bs[nt]=b0[nt*16+lr];
  float ssum[4]={0,0,0,0}, ssq[4]={0,0,0,0};
  const int base_row = blockIdx.x*512;
  const int b = base_row / (NS*NK);
  for (int ti=0;ti<TPW;ti++){
    const int R0 = base_row + (w*TPW+ti)*16;
    const int Ra = R0 + lr;
    const int idxp = grp[Ra];
    const float* frow = f + ((size_t)(b*NP+idxp))*64;
    f32x4 u0=*(const f32x4*)(frow + lg*8);
    f32x4 u1=*(const f32x4*)(frow + lg*8 + 4);
    f32x4 u2=*(const f32x4*)(frow + 32 + lg*8);
    f32x4 u3=*(const f32x4*)(frow + 36 + lg*8);
    u16x8 t0, t1;
#pragma unroll
    for (int j=0;j<4;j++){
      t0[j]=f2bf(u0[j]); t0[4+j]=f2bf(u1[j]);
      t1[j]=f2bf(u2[j]); t1[4+j]=f2bf(u3[j]);
    }
    u16x8 t2={0,0,0,0,0,0,0,0};
    if (lg==0){
      const int qidx = Ra >> 5;  // b*NS + s
      const float* pp = p + ((size_t)(b*NP+idxp))*3;
      const float* qq = qry + (size_t)qidx*3;
      t2[0]=f2bf(__fsub_rn(pp[0],qq[0]));
      t2[1]=f2bf(__fsub_rn(pp[1],qq[1]));
      t2[2]=f2bf(__fsub_rn(pp[2],qq[2]));
    }
    bf16x8 a0=__builtin_bit_cast(bf16x8,t0);
    bf16x8 a1=__builtin_bit_cast(bf16x8,t1);
    bf16x8 a2=__builtin_bit_cast(bf16x8,t2);
#pragma unroll
    for (int nt=0;nt<4;nt++){
      f32x4 acc={0,0,0,0};
      acc=__builtin_amdgcn_mfma_f32_16x16x32_bf16(a0,bw[0][nt],acc,0,0,0);
      acc=__builtin_amdgcn_mfma_f32_16x16x32_bf16(a1,bw[1][nt],acc,0,0,0);
      acc=__builtin_amdgcn_mfma_f32_16x16x32_bf16(a2,bw[2][nt],acc,0,0,0);
#pragma unroll
      for (int r=0;r<4;r++){
        float v = acc[r] + bs[nt];
        ssum[nt]+=v; ssq[nt]+=v*v;
        ybuf[(size_t)(R0 + lg*4 + r)*64 + nt*16 + lr] = f2bf(v);
      }
    }
  }
  float* slot = slots + (size_t)(blockIdx.x & 63)*256;
#pragma unroll
  for (int nt=0;nt<4;nt++){
    float s1=ssum[nt], s2=ssq[nt];
    s1 += __shfl_xor(s1,16); s1 += __shfl_xor(s1,32);
    s2 += __shfl_xor(s2,16); s2 += __shfl_xor(s2,32);
    if (lane<16){
      atomicAdd(slot + nt*16+lr, s1);
      atomicAdd(slot + 128 + nt*16+lr, s2);
    }
  }
}

// ---------------------------------------------------------------------------
// K5: finalize BN params for a layer; also re-zero slots for the next layer.
// ---------------------------------------------------------------------------
__global__ void finalize_kernel(float* __restrict__ slots,
                                const float* __restrict__ gamma,
                                const float* __restrict__ beta,
                                float* __restrict__ par, int Cc){
  const int c = threadIdx.x;  // 128 threads
  float s1=0.f, s2=0.f;
  for (int i=0;i<64;i++){ s1+=slots[i*256+c]; s2+=slots[i*256+128+c]; }
  const float invM = 1.0f/(float)NROWS;
  if (c<Cc){
    float mean = s1*invM;
    float var  = s2*invM - mean*mean;
    float scale = gamma[c]/sqrtf(var + 1e-5f);
    par[c]      = scale;
    par[128+c]  = beta[c] - mean*scale;
  }
  for (int i=0;i<64;i++){ slots[i*256+c]=0.f; slots[i*256+128+c]=0.f; }
}

// ---------------------------------------------------------------------------
// K6: layer1 = affine0+relu on y0, GEMM with W1 (64x64), stats; in-place y0->y1
// ---------------------------------------------------------------------------
__global__ __launch_bounds__(256) void gemm1_kernel(unsigned short* __restrict__ ybuf,
    const float* __restrict__ W, const float* __restrict__ bv,
    const float* __restrict__ par0, float* __restrict__ slots){
  const int tid=threadIdx.x, lane=tid&63, w=tid>>6;
  const int lg=lane>>4, lr=lane&15;
  float sc[2][8], sh[2][8];
#pragma unroll
  for (int kc=0;kc<2;kc++){
    int c0=kc*32+lg*8;
#pragma unroll
    for (int j=0;j<8;j++){ sc[kc][j]=par0[c0+j]; sh[kc][j]=par0[128+c0+j]; }
  }
  bf16x8 bw[2][4];
#pragma unroll
  for (int kc=0;kc<2;kc++)
#pragma unroll
    for (int nt=0;nt<4;nt++){
      u16x8 t;
#pragma unroll
      for (int j=0;j<8;j++){
        int k=kc*32+lg*8+j, n=nt*16+lr;
        t[j]=f2bf(W[k*64+n]);
      }
      bw[kc][nt]=__builtin_bit_cast(bf16x8,t);
    }
  float bs[4];
#pragma unroll
  for (int nt=0;nt<4;nt++) bs[nt]=bv[nt*16+lr];
  float ssum[4]={0,0,0,0}, ssq[4]={0,0,0,0};
  const int base_row = blockIdx.x*512;
  for (int ti=0;ti<TPW;ti++){
    const int R0 = base_row + (w*TPW+ti)*16;
    const unsigned short* yr = ybuf + (size_t)(R0+lr)*64;
    bf16x8 a[2];
#pragma unroll
    for (int kc=0;kc<2;kc++){
      u16x8 rv = *(const u16x8*)(yr + kc*32 + lg*8);
      u16x8 t;
#pragma unroll
      for (int j=0;j<8;j++){
        float v = bf2f(rv[j]);
        v = fmaxf(fmaf(v, sc[kc][j], sh[kc][j]), 0.f);
        t[j]=f2bf(v);
      }
      a[kc]=__builtin_bit_cast(bf16x8,t);
    }
#pragma unroll
    for (int nt=0;nt<4;nt++){
      f32x4 acc={0,0,0,0};
      acc=__builtin_amdgcn_mfma_f32_16x16x32_bf16(a[0],bw[0][nt],acc,0,0,0);
      acc=__builtin_amdgcn_mfma_f32_16x16x32_bf16(a[1],bw[1][nt],acc,0,0,0);
#pragma unroll
      for (int r=0;r<4;r++){
        float v = acc[r] + bs[nt];
        ssum[nt]+=v; ssq[nt]+=v*v;
        ybuf[(size_t)(R0 + lg*4 + r)*64 + nt*16 + lr] = f2bf(v);
      }
    }
  }
  float* slot = slots + (size_t)(blockIdx.x & 63)*256;
#pragma unroll
  for (int nt=0;nt<4;nt++){
    float s1=ssum[nt], s2=ssq[nt];
    s1 += __shfl_xor(s1,16); s1 += __shfl_xor(s1,32);
    s2 += __shfl_xor(s2,16); s2 += __shfl_xor(s2,32);
    if (lane<16){
      atomicAdd(slot + nt*16+lr, s1);
      atomicAdd(slot + 128 + nt*16+lr, s2);
    }
  }
}

// ---------------------------------------------------------------------------
// K7a (fused path): layer2 GEMM once -> stats2 + per-query max AND min of raw
// z2. max/min commute with the monotone BN2+relu applied later (scale>0 uses
// max, scale<0 uses min; correctly-rounded fmaf is monotone in z).
// ---------------------------------------------------------------------------
__global__ __launch_bounds__(256) void gemm2fused_kernel(const unsigned short* __restrict__ ybuf,
    const float* __restrict__ W, const float* __restrict__ bv,
    const float* __restrict__ par1, float* __restrict__ slots,
    float* __restrict__ zmax, float* __restrict__ zmin){
  const int tid=threadIdx.x, lane=tid&63, w=tid>>6;
  const int lg=lane>>4, lr=lane&15;
  float sc[2][8], sh[2][8];
#pragma unroll
  for (int kc=0;kc<2;kc++){
    int c0=kc*32+lg*8;
#pragma unroll
    for (int j=0;j<8;j++){ sc[kc][j]=par1[c0+j]; sh[kc][j]=par1[128+c0+j]; }
  }
  bf16x8 bw[2][8];
#pragma unroll
  for (int kc=0;kc<2;kc++)
#pragma unroll
    for (int nt=0;nt<8;nt++){
      u16x8 t;
#pragma unroll
      for (int j=0;j<8;j++){
        int k=kc*32+lg*8+j, n=nt*16+lr;
        t[j]=f2bf(W[k*128+n]);
      }
      bw[kc][nt]=__builtin_bit_cast(bf16x8,t);
    }
  float bs[8], ssum[8], ssq[8], qmax[8], qmin[8];
#pragma unroll
  for (int nt=0;nt<8;nt++){
    bs[nt]=bv[nt*16+lr]; ssum[nt]=0.f; ssq[nt]=0.f;
    qmax[nt]=-3e38f; qmin[nt]=3e38f;
  }
  const int base_row = blockIdx.x*512;
  for (int ti=0;ti<TPW;ti++){
    const int R0 = base_row + (w*TPW+ti)*16;
    const unsigned short* yr = ybuf + (size_t)(R0+lr)*64;
    bf16x8 a[2];
#pragma unroll
    for (int kc=0;kc<2;kc++){
      u16x8 rv = *(const u16x8*)(yr + kc*32 + lg*8);
      u16x8 t;
#pragma unroll
      for (int j=0;j<8;j++){
        float v = bf2f(rv[j]);
        v = fmaxf(fmaf(v, sc[kc][j], sh[kc][j]), 0.f);
        t[j]=f2bf(v);
      }
      a[kc]=__builtin_bit_cast(bf16x8,t);
    }
#pragma unroll
    for (int nt=0;nt<8;nt++){
      f32x4 acc={0,0,0,0};
      acc=__builtin_amdgcn_mfma_f32_16x16x32_bf16(a[0],bw[0][nt],acc,0,0,0);
      acc=__builtin_amdgcn_mfma_f32_16x16x32_bf16(a[1],bw[1][nt],acc,0,0,0);
#pragma unroll
      for (int r=0;r<4;r++){
        float v = acc[r] + bs[nt];
        ssum[nt]+=v; ssq[nt]+=v*v;
        qmax[nt]=fmaxf(qmax[nt],v); qmin[nt]=fminf(qmin[nt],v);
      }
    }
    if (ti & 1){
      const int q = R0 >> 5;   // rows [32q,32q+32) covered by tiles ti-1,ti
#pragma unroll
      for (int nt=0;nt<8;nt++){
        float mx=qmax[nt], mn=qmin[nt];
        mx = fmaxf(mx, __shfl_xor(mx,16)); mx = fmaxf(mx, __shfl_xor(mx,32));
        mn = fminf(mn, __shfl_xor(mn,16)); mn = fminf(mn, __shfl_xor(mn,32));
        if (lane<16){
          zmax[(size_t)q*128 + nt*16 + lane] = mx;
          zmin[(size_t)q*128 + nt*16 + lane] = mn;
        }
        qmax[nt]=-3e38f; qmin[nt]=3e38f;
      }
    }
  }
  float* slot = slots + (size_t)(blockIdx.x & 63)*256;
#pragma unroll
  for (int nt=0;nt<8;nt++){
    float s1=ssum[nt], s2=ssq[nt];
    s1 += __shfl_xor(s1,16); s1 += __shfl_xor(s1,32);
    s2 += __shfl_xor(s2,16); s2 += __shfl_xor(s2,32);
    if (lane<16){
      atomicAdd(slot + nt*16+lr, s1);
      atomicAdd(slot + 128 + nt*16+lr, s2);
    }
  }
}

// K7b (fused path): apply BN2+relu to the per-query extremum.
__global__ void bn2max_kernel(const float* __restrict__ zmax,
                              const float* __restrict__ zmin,
                              const float* __restrict__ par2,
                              float* __restrict__ fout){
  int idx = blockIdx.x*256 + threadIdx.x;     // NB*NS*128 = 2M
  if (idx < NB*NS*128){
    int c = idx & 127;
    float scale = par2[c], shift = par2[128+c];
    float z = (scale > 0.f) ? zmax[idx] : zmin[idx];
    fout[idx] = fmaxf(fmaf(z, scale, shift), 0.f);
  }
}

// ---------------------------------------------------------------------------
// K7/K8 (fallback path, used when ws too small): stats pass + recompute+max.
// ---------------------------------------------------------------------------
__global__ __launch_bounds__(256) void gemm2stats_kernel(const unsigned short* __restrict__ ybuf,
    const float* __restrict__ W, const float* __restrict__ bv,
    const float* __restrict__ par1, float* __restrict__ slots){
  const int tid=threadIdx.x, lane=tid&63, w=tid>>6;
  const int lg=lane>>4, lr=lane&15;
  float sc[2][8], sh[2][8];
#pragma unroll
  for (int kc=0;kc<2;kc++){
    int c0=kc*32+lg*8;
#pragma unroll
    for (int j=0;j<8;j++){ sc[kc][j]=par1[c0+j]; sh[kc][j]=par1[128+c0+j]; }
  }
  bf16x8 bw[2][8];
#pragma unroll
  for (int kc=0;kc<2;kc++)
#pragma unroll
    for (int nt=0;nt<8;nt++){
      u16x8 t;
#pragma unroll
      for (int j=0;j<8;j++){
        int k=kc*32+lg*8+j, n=nt*16+lr;
        t[j]=f2bf(W[k*128+n]);
      }
      bw[kc][nt]=__builtin_bit_cast(bf16x8,t);
    }
  float bs[8], ssum[8], ssq[8];
#pragma unroll
  for (int nt=0;nt<8;nt++){ bs[nt]=bv[nt*16+lr]; ssum[nt]=0.f; ssq[nt]=0.f; }
  const int base_row = blockIdx.x*512;
  for (int ti=0;ti<TPW;ti++){
    const int R0 = base_row + (w*TPW+ti)*16;
    const unsigned short* yr = ybuf + (size_t)(R0+lr)*64;
    bf16x8 a[2];
#pragma unroll
    for (int kc=0;kc<2;kc++){
      u16x8 rv = *(const u16x8*)(yr + kc*32 + lg*8);
      u16x8 t;
#pragma unroll
      for (int j=0;j<8;j++){
        float v = bf2f(rv[j]);
        v = fmaxf(fmaf(v, sc[kc][j], sh[kc][j]), 0.f);
        t[j]=f2bf(v);
      }
      a[kc]=__builtin_bit_cast(bf16x8,t);
    }
#pragma unroll
    for (int nt=0;nt<8;nt++){
      f32x4 acc={0,0,0,0};
      acc=__builtin_amdgcn_mfma_f32_16x16x32_bf16(a[0],bw[0][nt],acc,0,0,0);
      acc=__builtin_amdgcn_mfma_f32_16x16x32_bf16(a[1],bw[1][nt],acc,0,0,0);
#pragma unroll
      for (int r=0;r<4;r++){
        float v = acc[r] + bs[nt];
        ssum[nt]+=v; ssq[nt]+=v*v;
      }
    }
  }
  float* slot = slots + (size_t)(blockIdx.x & 63)*256;
#pragma unroll
  for (int nt=0;nt<8;nt++){
    float s1=ssum[nt], s2=ssq[nt];
    s1 += __shfl_xor(s1,16); s1 += __shfl_xor(s1,32);
    s2 += __shfl_xor(s2,16); s2 += __shfl_xor(s2,32);
    if (lane<16){
      atomicAdd(slot + nt*16+lr, s1);
      atomicAdd(slot + 128 + nt*16+lr, s2);
    }
  }
}

#define QPW 8
__global__ __launch_bounds__(256) void gemm2max_kernel(const unsigned short* __restrict__ ybuf,
    const float* __restrict__ W, const float* __restrict__ bv,
    const float* __restrict__ par1, const float* __restrict__ par2,
    float* __restrict__ fout){
  const int tid=threadIdx.x, lane=tid&63, w=tid>>6;
  const int lg=lane>>4, lr=lane&15;
  float sc1[2][8], sh1[2][8];
#pragma unroll
  for (int kc=0;kc<2;kc++){
    int c0=kc*32+lg*8;
#pragma unroll
    for (int j=0;j<8;j++){ sc1[kc][j]=par1[c0+j]; sh1[kc][j]=par1[128+c0+j]; }
  }
  float sc2[8], sh2[8], bs[8];
#pragma unroll
  for (int nt=0;nt<8;nt++){
    int n=nt*16+lr;
    sc2[nt]=par2[n]; sh2[nt]=par2[128+n]; bs[nt]=bv[n];
  }
  bf16x8 bw[2][8];
#pragma unroll
  for (int kc=0;kc<2;kc++)
#pragma unroll
    for (int nt=0;nt<8;nt++){
      u16x8 t;
#pragma unroll
      for (int j=0;j<8;j++){
        int k=kc*32+lg*8+j, n=nt*16+lr;
        t[j]=f2bf(W[k*128+n]);
      }
      bw[kc][nt]=__builtin_bit_cast(bf16x8,t);
    }
  const int qbase = blockIdx.x*(4*QPW) + w*QPW;
  for (int qi=0;qi<QPW;qi++){
    const int gq = qbase + qi;
    float qmax[8];
#pragma unroll
    for (int nt=0;nt<8;nt++) qmax[nt]=-1e30f;
#pragma unroll
    for (int half=0; half<2; half++){
      const int R0 = gq*32 + half*16;
      const unsigned short* yr = ybuf + (size_t)(R0+lr)*64;
      bf16x8 a[2];
#pragma unroll
      for (int kc=0;kc<2;kc++){
        u16x8 rv = *(const u16x8*)(yr + kc*32 + lg*8);
        u16x8 t;
#pragma unroll
        for (int j=0;j<8;j++){
          float v = bf2f(rv[j]);
          v = fmaxf(fmaf(v, sc1[kc][j], sh1[kc][j]), 0.f);
          t[j]=f2bf(v);
        }
        a[kc]=__builtin_bit_cast(bf16x8,t);
      }
#pragma unroll
      for (int nt=0;nt<8;nt++){
        f32x4 acc={0,0,0,0};
        acc=__builtin_amdgcn_mfma_f32_16x16x32_bf16(a[0],bw[0][nt],acc,0,0,0);
        acc=__builtin_amdgcn_mfma_f32_16x16x32_bf16(a[1],bw[1][nt],acc,0,0,0);
        float m=-1e30f;
#pragma unroll
        for (int r=0;r<4;r++){
          float v = acc[r] + bs[nt];
          v = fmaxf(fmaf(v, sc2[nt], sh2[nt]), 0.f);
          m = fmaxf(m, v);
        }
        m = fmaxf(m, __shfl_xor(m,16));
        m = fmaxf(m, __shfl_xor(m,32));
        qmax[nt] = fmaxf(qmax[nt], m);
      }
    }
    if (lane<16){
#pragma unroll
      for (int nt=0;nt<8;nt++)
        fout[(size_t)gq*128 + nt*16 + lane] = qmax[nt];
    }
  }
}

// ---------------------------------------------------------------------------
extern "C" void kernel_launch(void* const* d_in, const int* in_sizes, int n_in,
                              void* d_out, int out_size, void* d_ws, size_t ws_size,
                              hipStream_t stream){
  const float* f   = (const float*)d_in[0];
  const float* p   = (const float*)d_in[1];
  const float* W0  = (const float*)d_in[2];
  const float* b0  = (const float*)d_in[3];
  const float* g0  = (const float*)d_in[4];
  const float* be0 = (const float*)d_in[5];
  const float* W1  = (const float*)d_in[6];
  const float* b1  = (const float*)d_in[7];
  const float* g1  = (const float*)d_in[8];
  const float* be1 = (const float*)d_in[9];
  const float* W2  = (const float*)d_in[10];
  const float* b2  = (const float*)d_in[11];
  const float* g2  = (const float*)d_in[12];
  const float* be2 = (const float*)d_in[13];

  float* out = (float*)d_out;
  float* qry = out + (size_t)NB*NS*128;   // second output: qry_pnt

  char* w = (char*)d_ws;
  const size_t off_ybuf  = (size_t)2*1024*1024;
  const size_t off_slots = off_ybuf + (size_t)NROWS*64*2;
  const size_t off_par   = off_slots + (size_t)64*256*4;
  const size_t off_zmm   = (off_par + 3*256*4 + 1023) & ~(size_t)1023;
  const size_t need_fused = off_zmm + (size_t)NB*NS*128*2*4;

  int* grp = (int*)w;
  unsigned short* ybuf = (unsigned short*)(w + off_ybuf);
  float* slots = (float*)(w + off_slots);
  float* par0 = (float*)(w + off_par);
  float* par1 = par0 + 256;
  float* par2 = par1 + 256;
  float* zmax = (float*)(w + off_zmm);
  float* zmin = zmax + (size_t)NB*NS*128;

  fps_kernel<<<NB, FPS_T, 0, stream>>>(p, qry);
  ballq_kernel<<<NB*(NS/8), BQ_T, 0, stream>>>(p, qry, grp);
  zero_slots_kernel<<<64, 256, 0, stream>>>(slots);
  gemm0_kernel<<<NROWS/512, 256, 0, stream>>>(f, p, qry, grp, W0, b0, ybuf, slots);
  finalize_kernel<<<1, 128, 0, stream>>>(slots, g0, be0, par0, 64);
  gemm1_kernel<<<NROWS/512, 256, 0, stream>>>(ybuf, W1, b1, par0, slots);
  finalize_kernel<<<1, 128, 0, stream>>>(slots, g1, be1, par1, 64);
  if (ws_size >= need_fused){
    gemm2fused_kernel<<<NROWS/512, 256, 0, stream>>>(ybuf, W2, b2, par1, slots, zmax, zmin);
    finalize_kernel<<<1, 128, 0, stream>>>(slots, g2, be2, par2, 128);
    bn2max_kernel<<<(NB*NS*128)/256, 256, 0, stream>>>(zmax, zmin, par2, out);
  } else {
    gemm2stats_kernel<<<NROWS/512, 256, 0, stream>>>(ybuf, W2, b2, par1, slots);
    finalize_kernel<<<1, 128, 0, stream>>>(slots, g2, be2, par2, 128);
    gemm2max_kernel<<<NB*NS/(4*QPW), 256, 0, stream>>>(ybuf, W2, b2, par1, par2, out);
  }
}